// Round 11
// baseline (290.209 us; speedup 1.0000x reference)
//
#include <hip/hip_runtime.h>
#include <hip/hip_bf16.h>
#include <stdint.h>

// FoodRiskGNN: 2-layer GraphSAGE (mean aggr), N=100000, E=1600000, 64->128->64.
// Round-11: r10 structure + (a) slim k_part (u16 index staging, 28.5KB LDS,
// 4 blocks/CU) and (b) 16-deep predicated gather batches in k_aggs.
//   memset hist -> k_prep{cast|bhist|wprep} -> scanb -> part
//   agg1 = mean-gather(xb)                  [k_aggs<0>]
//   h=relu([agg1|xb]@W1+b1); [y2|z2]=h@[Wl2|Wr2]   [k_mmf, h in LDS only]
//   out  = sigmoid(mean-gather(y2) + z2 + b2)      [k_aggs<1>]

#define NBMAX 784
#define BCAP 3584  // max edges per 128-node bucket (mean 2048, sd 45; +34 sigma)

typedef __bf16 bf16x8 __attribute__((ext_vector_type(8)));
typedef float f32x4 __attribute__((ext_vector_type(4)));

__device__ __forceinline__ float ldb(const unsigned short* p) {
  return __uint_as_float(((unsigned int)*p) << 16);
}

__device__ __forceinline__ unsigned short bf16u(float f) {
  __hip_bfloat16 h = __float2bfloat16(f);
  return *(unsigned short*)&h;
}

// ---- grid-split prep: [0,castB): x->xb bf16; [castB,castB+histB): bucket
//      histogram; last 16 blocks: pack W1/W2 into MFMA B-frag order ----
__global__ __launch_bounds__(256) void k_prep(const float* __restrict__ x,
                                              unsigned short* __restrict__ xb,
                                              const int* __restrict__ dst,
                                              unsigned int* __restrict__ hist,
                                              const float* __restrict__ Wl1,
                                              const float* __restrict__ Wr1,
                                              const float* __restrict__ Wl2,
                                              const float* __restrict__ Wr2,
                                              unsigned short* __restrict__ W1p,
                                              unsigned short* __restrict__ W2p,
                                              int N, int E, int NB, int castB, int histB) {
  __shared__ unsigned int lh[NBMAX];
  const int tid = threadIdx.x;
  const int b = blockIdx.x;
  if (b < castB) {
    int i = b * 256 + tid;
    if (i < N * 16) {
      int n = i >> 4, c4 = (i & 15) << 2;
      float4 v = *(const float4*)(x + (size_t)n * 64 + c4);
      unsigned int u0 = (unsigned int)bf16u(v.x) | ((unsigned int)bf16u(v.y) << 16);
      unsigned int u1 = (unsigned int)bf16u(v.z) | ((unsigned int)bf16u(v.w) << 16);
      *(uint2*)(xb + (size_t)n * 64 + c4) = make_uint2(u0, u1);
    }
  } else if (b < castB + histB) {
    for (int i = tid; i < NB; i += 256) lh[i] = 0;
    __syncthreads();
    const int e0 = (b - castB) * 16384;
    const int m = min(16384, E - e0);
    for (int i = tid; i < m; i += 256) atomicAdd(&lh[(unsigned int)dst[e0 + i] >> 7], 1u);
    __syncthreads();
    for (int i = tid; i < NB; i += 256) {
      unsigned int c = lh[i];
      if (c) atomicAdd(&hist[i], c);
    }
  } else {
    int f = (b - castB - histB) * 256 + tid;  // 0..4095
    if (f < 4096) {
      int mat = f >> 11;
      int fr = f & 2047;
      int lane = fr & 63;
      int ntkb = fr >> 6;
      int nt = ntkb >> 2, kb = ntkb & 3;
      int col = (nt << 4) + (lane & 15);
      int k0 = (kb << 5) + ((lane >> 4) << 3);
      unsigned short v[8];
#pragma unroll
      for (int i = 0; i < 8; ++i) {
        int k = k0 + i;
        float val;
        if (mat == 0) val = (k < 64) ? Wl1[k * 128 + col] : Wr1[(k - 64) * 128 + col];
        else          val = (col < 64) ? Wl2[k * 64 + col] : Wr2[k * 64 + (col - 64)];
        v[i] = bf16u(val);
      }
      *(uint4*)((mat ? W2p : W1p) + (size_t)fr * 8) = *(const uint4*)v;
    }
  }
}

// ---- scan NB bucket counts -> base (exclusive) + cursor init. 1 wave. ----
__global__ void k_scanb(const unsigned int* __restrict__ hist, unsigned int* __restrict__ base,
                        unsigned int* __restrict__ cursor, int NB) {
  const int lane = threadIdx.x;
  unsigned int running = 0;
  for (int b0 = 0; b0 < NB; b0 += 64) {
    int i = b0 + lane;
    unsigned int v = (i < NB) ? hist[i] : 0;
    unsigned int s = v;
#pragma unroll
    for (int off = 1; off < 64; off <<= 1) {
      unsigned int t = __shfl_up(s, off);
      if (lane >= off) s += t;
    }
    if (i < NB) {
      base[i] = running + s - v;
      cursor[i] = running + s - v;
    }
    running += __shfl(s, 63);
  }
  if (lane == 0) base[NB] = running;
}

// ---- partition edges into bucket regions; payload = src | (dst&127)<<25 ----
// Slim staging: u16 local edge-index permutation; write-out re-reads dst/src
// (permutation within a 32KB window -> L1). LDS 28.5KB -> 4 blocks/CU.
__global__ __launch_bounds__(512) void k_part(const int* __restrict__ src,
                                              const int* __restrict__ dst,
                                              unsigned int* __restrict__ cursor,
                                              unsigned int* __restrict__ bkt, int E, int NB) {
  __shared__ unsigned int histL[NBMAX], lbase[NBMAX], gpos[NBMAX], lcur[NBMAX];  // 12.5KB
  __shared__ unsigned short stage[8192];                                          // 16KB
  const int tid = threadIdx.x;
  const int e0 = blockIdx.x * 8192;
  const int m = min(8192, E - e0);
  for (int b = tid; b < NB; b += 512) { histL[b] = 0; lcur[b] = 0; }
  __syncthreads();
  for (int i = tid; i < m; i += 512) atomicAdd(&histL[(unsigned int)dst[e0 + i] >> 7], 1u);
  __syncthreads();
  if (tid < 64) {  // wave-0 exclusive scan of histL -> lbase
    unsigned int running = 0;
    for (int b0 = 0; b0 < NB; b0 += 64) {
      int i = b0 + tid;
      unsigned int v = (i < NB) ? histL[i] : 0;
      unsigned int s = v;
#pragma unroll
      for (int off = 1; off < 64; off <<= 1) {
        unsigned int t = __shfl_up(s, off);
        if (tid >= off) s += t;
      }
      if (i < NB) lbase[i] = running + s - v;
      running += __shfl(s, 63);
    }
  }
  __syncthreads();
  for (int b = tid; b < NB; b += 512) {
    unsigned int c = histL[b];
    gpos[b] = c ? atomicAdd(&cursor[b], c) : 0u;
  }
  for (int i = tid; i < m; i += 512) {
    unsigned int b = (unsigned int)dst[e0 + i] >> 7;
    unsigned int p = lbase[b] + atomicAdd(&lcur[b], 1u);
    stage[p] = (unsigned short)i;
  }
  __syncthreads();
  for (int i = tid; i < m; i += 512) {
    int idx = (int)stage[i];
    int d = dst[e0 + idx];          // L1-resident re-read
    int s = src[e0 + idx];
    unsigned int b = (unsigned int)d >> 7;
    bkt[gpos[b] + (unsigned int)i - lbase[b]] =
        (unsigned int)s | ((unsigned int)(d & 127) << 25);
  }
}

// ---- atomic-free bucketed mean-aggregation (linear rows) ----
// Block = 128-node bucket. Phase A: LDS counting-sort by local dst (uint
// atomics). Phase B: wave owns 16 nodes; lane = channel; predicated 16-deep
// full-row (128B) gather batches. EPI=0: write bf16 rows. EPI=1: fused
// out = sigmoid(mean + z2 + b2), f32.
template <int EPI>
__global__ __launch_bounds__(512) void k_aggs(const unsigned short* __restrict__ feat,  // bf16[N][64]
                                              const unsigned int* __restrict__ bkt,
                                              const unsigned int* __restrict__ base,
                                              unsigned short* __restrict__ outRows,
                                              const float* __restrict__ z2,
                                              const float* __restrict__ b2,
                                              float* __restrict__ outF, int N) {
  __shared__ unsigned int pbufA[BCAP];
  __shared__ unsigned int pbufB[BCAP];
  __shared__ unsigned int hist[128], lofs[128], cur[128];
  const int tid = threadIdx.x;
  const int lane = tid & 63;
  const int w = tid >> 6;  // 8 waves
  const int nodelo = blockIdx.x << 7;
  if (tid < 128) hist[tid] = 0;
  const int ebeg = (int)base[blockIdx.x];
  int m = (int)base[blockIdx.x + 1] - ebeg;
  m = (m > BCAP) ? BCAP : m;
  float bias = 0.f;
  if (EPI == 1) bias = b2[lane];
  __syncthreads();
  for (int i = tid; i < m; i += 512) {
    unsigned int t = bkt[ebeg + i];
    pbufA[i] = t;
    atomicAdd(&hist[t >> 25], 1u);
  }
  __syncthreads();
  if (tid < 64) {
    unsigned int v0 = hist[tid], v1 = hist[tid + 64];
    unsigned int s0 = v0, s1 = v1;
#pragma unroll
    for (int off = 1; off < 64; off <<= 1) {
      unsigned int t0 = __shfl_up(s0, off);
      unsigned int t1 = __shfl_up(s1, off);
      if (tid >= off) { s0 += t0; s1 += t1; }
    }
    unsigned int tot0 = __shfl(s0, 63);
    lofs[tid]      = s0 - v0;
    lofs[tid + 64] = tot0 + s1 - v1;
    cur[tid]       = s0 - v0;
    cur[tid + 64]  = tot0 + s1 - v1;
  }
  __syncthreads();
  for (int i = tid; i < m; i += 512) {
    unsigned int t = pbufA[i];
    unsigned int p = atomicAdd(&cur[t >> 25], 1u);
    pbufB[p] = t;
  }
  __syncthreads();
  // Phase B: predicated 16-deep full-row gather (mean degree = 16)
  for (int q = 0; q < 16; ++q) {
    const int r = (w << 4) + q;  // local node, wave-uniform
    const int c = __builtin_amdgcn_readfirstlane((int)hist[r]);
    const int o = __builtin_amdgcn_readfirstlane((int)lofs[r]);
    float acc = 0.f;
    for (int e = 0; e < c; e += 16) {
      int si[16];
      float mk[16];
#pragma unroll
      for (int k = 0; k < 16; ++k) {
        int ee = e + k;
        int ec = (ee < c) ? ee : (c - 1);
        si[k] = __builtin_amdgcn_readfirstlane((int)(pbufB[o + ec] & 0x1FFFFFFu));
        mk[k] = (ee < c) ? 1.f : 0.f;
      }
      float f[16];
#pragma unroll
      for (int k = 0; k < 16; ++k) f[k] = ldb(feat + ((size_t)si[k] << 6) + lane);
#pragma unroll
      for (int k = 0; k < 16; ++k) acc = fmaf(f[k], mk[k], acc);
    }
    const int node = nodelo + r;
    if (node < N) {
      float sc = c ? (1.f / (float)c) : 0.f;
      float v = acc * sc;
      if (EPI == 0) {
        outRows[((size_t)node << 6) + lane] = bf16u(v);
      } else {
        float t = v + z2[((size_t)node << 6) + lane] + bias;
        outF[((size_t)node << 6) + lane] = 1.f / (1.f + __expf(-t));
      }
    }
  }
}

// ---- fused MFMA: h = relu([agg|xb]@W1+b1) (LDS only); [y2|z2] = h@[Wl2|Wr2] ----
__global__ __launch_bounds__(256) void k_mmf(const unsigned short* __restrict__ agg,
                                             const unsigned short* __restrict__ xb,
                                             const unsigned short* __restrict__ W1p,
                                             const unsigned short* __restrict__ W2p,
                                             const float* __restrict__ b1,
                                             unsigned short* __restrict__ y2,
                                             float* __restrict__ z2, int N) {
  __shared__ __align__(16) unsigned short sH[64][136];  // 17.4 KB
  __shared__ __align__(16) unsigned short sY[64][72];   //  9.2 KB
  __shared__ __align__(16) float sZ[64][68];            // 17.4 KB
  const int tid = threadIdx.x;
  const int lane = tid & 63;
  const int w = tid >> 6;
  const int n0 = blockIdx.x << 6;
  const int row16 = lane & 15;
  const int kgrp = lane >> 4;
  int node = n0 + (w << 4) + row16;
  if (node >= N) node = N - 1;

  // ---- layer 1 ----
  bf16x8 a[4];
  {
    const unsigned short* ra = agg + ((size_t)node << 6);
    const unsigned short* rx = xb + ((size_t)node << 6);
    a[0] = *(const bf16x8*)(ra + kgrp * 8);
    a[1] = *(const bf16x8*)(ra + 32 + kgrp * 8);
    a[2] = *(const bf16x8*)(rx + kgrp * 8);
    a[3] = *(const bf16x8*)(rx + 32 + kgrp * 8);
  }
  const bf16x8* Wp1 = (const bf16x8*)W1p;
#pragma unroll
  for (int nt = 0; nt < 8; ++nt) {
    f32x4 acc = {0.f, 0.f, 0.f, 0.f};
#pragma unroll
    for (int kb = 0; kb < 4; ++kb) {
      bf16x8 b = Wp1[(nt * 4 + kb) * 64 + lane];
      acc = __builtin_amdgcn_mfma_f32_16x16x32_bf16(a[kb], b, acc, 0, 0, 0);
    }
    const int col = (nt << 4) + row16;
    const float bias = b1[col];
#pragma unroll
    for (int r = 0; r < 4; ++r) {
      int lrow = (w << 4) + (kgrp << 2) + r;
      sH[lrow][col] = bf16u(fmaxf(acc[r] + bias, 0.f));
    }
  }
  __syncthreads();
  // ---- layer 2: A-frags from LDS h-tile ----
  bf16x8 h4[4];
  {
    const int hr = (w << 4) + row16;
#pragma unroll
    for (int kb = 0; kb < 4; ++kb)
      h4[kb] = *(const bf16x8*)(&sH[hr][kb * 32 + kgrp * 8]);
  }
  const bf16x8* Wp2 = (const bf16x8*)W2p;
#pragma unroll
  for (int nt = 0; nt < 8; ++nt) {
    f32x4 acc = {0.f, 0.f, 0.f, 0.f};
#pragma unroll
    for (int kb = 0; kb < 4; ++kb) {
      bf16x8 b = Wp2[(nt * 4 + kb) * 64 + lane];
      acc = __builtin_amdgcn_mfma_f32_16x16x32_bf16(h4[kb], b, acc, 0, 0, 0);
    }
    const int col = (nt << 4) + row16;
#pragma unroll
    for (int r = 0; r < 4; ++r) {
      int lrow = (w << 4) + (kgrp << 2) + r;
      if (nt < 4) sY[lrow][col] = bf16u(acc[r]);
      else        sZ[lrow][col - 64] = acc[r];
    }
  }
  __syncthreads();
  // y2: 64 rows x 64 bf16 = 512 x 16B
#pragma unroll
  for (int it = 0; it < 2; ++it) {
    int idx = it * 256 + tid;
    int r = idx >> 3, sub = idx & 7;
    int nn = n0 + r;
    if (nn < N)
      *(uint4*)((char*)(y2 + ((size_t)nn << 6)) + sub * 16) =
          *(const uint4*)((char*)&sY[r][0] + sub * 16);
  }
  // z2: 64 rows x 64 f32 = 1024 x 16B
#pragma unroll
  for (int it = 0; it < 4; ++it) {
    int idx = it * 256 + tid;
    int r = idx >> 4, sub = idx & 15;
    int nn = n0 + r;
    if (nn < N)
      *(uint4*)((char*)(z2 + ((size_t)nn << 6)) + sub * 16) =
          *(const uint4*)((char*)&sZ[r][0] + sub * 16);
  }
}

extern "C" void kernel_launch(void* const* d_in, const int* in_sizes, int n_in,
                              void* d_out, int out_size, void* d_ws, size_t ws_size,
                              hipStream_t stream) {
  const float* x   = (const float*)d_in[0];
  const int*   ei  = (const int*)d_in[1];
  const float* Wl1 = (const float*)d_in[2];
  const float* Wr1 = (const float*)d_in[3];
  const float* b1  = (const float*)d_in[4];
  const float* Wl2 = (const float*)d_in[5];
  const float* Wr2 = (const float*)d_in[6];
  const float* b2  = (const float*)d_in[7];
  float* out = (float*)d_out;

  const int N = in_sizes[0] / 64;
  const int E = in_sizes[1] / 2;
  int NB = (N + 127) >> 7;
  if (NB > NBMAX) NB = NBMAX;
  const int* src = ei;
  const int* dst = ei + E;

  char* wp = (char*)d_ws;
  auto take = [&](size_t bytes) {
    char* p = wp;
    wp += (bytes + 255) & ~(size_t)255;
    return p;
  };
  unsigned int* hist   = (unsigned int*)take((size_t)NBMAX * 4);
  unsigned int* base   = (unsigned int*)take((size_t)(NBMAX + 1) * 4);
  unsigned int* cursor = (unsigned int*)take((size_t)NBMAX * 4);
  unsigned int* bkt    = (unsigned int*)take((size_t)E * 4);
  unsigned short* W1p  = (unsigned short*)take(128 * 128 * 2);
  unsigned short* W2p  = (unsigned short*)take(128 * 128 * 2);
  unsigned short* xb   = (unsigned short*)take((size_t)N * 64 * 2);
  unsigned short* agg  = (unsigned short*)take((size_t)N * 64 * 2);
  unsigned short* y2   = (unsigned short*)take((size_t)N * 64 * 2);
  float* z2            = (float*)take((size_t)N * 64 * 4);

  hipMemsetAsync(hist, 0, (size_t)NBMAX * 4, stream);

  const int castB = (N * 16 + 255) / 256;
  const int histB = (E + 16383) / 16384;
  k_prep<<<castB + histB + 16, 256, 0, stream>>>(x, xb, dst, hist, Wl1, Wr1, Wl2, Wr2,
                                                 W1p, W2p, N, E, NB, castB, histB);
  k_scanb<<<1, 64, 0, stream>>>(hist, base, cursor, NB);
  k_part<<<(E + 8191) / 8192, 512, 0, stream>>>(src, dst, cursor, bkt, E, NB);

  const int nb64 = (N + 63) / 64;
  k_aggs<0><<<NB, 512, 0, stream>>>(xb, bkt, base, agg, nullptr, nullptr, nullptr, N);
  k_mmf<<<nb64, 256, 0, stream>>>(agg, xb, W1p, W2p, b1, y2, z2, N);
  k_aggs<1><<<NB, 512, 0, stream>>>(y2, bkt, base, nullptr, z2, b2, out, N);
}

// Round 12
// 252.341 us; speedup vs baseline: 1.1501x; 1.1501x over previous
//
#include <hip/hip_runtime.h>
#include <hip/hip_bf16.h>
#include <stdint.h>

// FoodRiskGNN: 2-layer GraphSAGE (mean aggr), N=100000, E=1600000, 64->128->64.
// Round-12: revert gather loop to proven r5/r6 multi-tail form (predication
// was the r10/r11 regression); sort-once-reuse-twice (pass 0 writes sorted
// edges + degrees back, pass 1 skips the counting sort); keep slim k_part,
// fused k_mmf, fused sigmoid epilogue.
//   memset hist -> k_prep{cast|bhist|wprep} -> scanb -> part
//   agg1 = mean-gather(xb); write sorted bkt + degs   [k_aggs<0>]
//   h=relu([agg1|xb]@W1+b1); [y2|z2]=h@[Wl2|Wr2]      [k_mmf, h LDS-only]
//   out  = sigmoid(mean-gather(y2) + z2 + b2)         [k_aggs<1>, no sort]

#define NBMAX 784
#define BCAP 3584  // max edges per 128-node bucket (mean 2048, sd 45; +34 sigma)

typedef __bf16 bf16x8 __attribute__((ext_vector_type(8)));
typedef float f32x4 __attribute__((ext_vector_type(4)));

__device__ __forceinline__ float ldb(const unsigned short* p) {
  return __uint_as_float(((unsigned int)*p) << 16);
}

__device__ __forceinline__ unsigned short bf16u(float f) {
  __hip_bfloat16 h = __float2bfloat16(f);
  return *(unsigned short*)&h;
}

// ---- grid-split prep: [0,castB): x->xb bf16; [castB,castB+histB): bucket
//      histogram; last 16 blocks: pack W1/W2 into MFMA B-frag order ----
__global__ __launch_bounds__(256) void k_prep(const float* __restrict__ x,
                                              unsigned short* __restrict__ xb,
                                              const int* __restrict__ dst,
                                              unsigned int* __restrict__ hist,
                                              const float* __restrict__ Wl1,
                                              const float* __restrict__ Wr1,
                                              const float* __restrict__ Wl2,
                                              const float* __restrict__ Wr2,
                                              unsigned short* __restrict__ W1p,
                                              unsigned short* __restrict__ W2p,
                                              int N, int E, int NB, int castB, int histB) {
  __shared__ unsigned int lh[NBMAX];
  const int tid = threadIdx.x;
  const int b = blockIdx.x;
  if (b < castB) {
    int i = b * 256 + tid;
    if (i < N * 16) {
      int n = i >> 4, c4 = (i & 15) << 2;
      float4 v = *(const float4*)(x + (size_t)n * 64 + c4);
      unsigned int u0 = (unsigned int)bf16u(v.x) | ((unsigned int)bf16u(v.y) << 16);
      unsigned int u1 = (unsigned int)bf16u(v.z) | ((unsigned int)bf16u(v.w) << 16);
      *(uint2*)(xb + (size_t)n * 64 + c4) = make_uint2(u0, u1);
    }
  } else if (b < castB + histB) {
    for (int i = tid; i < NB; i += 256) lh[i] = 0;
    __syncthreads();
    const int e0 = (b - castB) * 16384;
    const int m = min(16384, E - e0);
    for (int i = tid; i < m; i += 256) atomicAdd(&lh[(unsigned int)dst[e0 + i] >> 7], 1u);
    __syncthreads();
    for (int i = tid; i < NB; i += 256) {
      unsigned int c = lh[i];
      if (c) atomicAdd(&hist[i], c);
    }
  } else {
    int f = (b - castB - histB) * 256 + tid;  // 0..4095
    if (f < 4096) {
      int mat = f >> 11;
      int fr = f & 2047;
      int lane = fr & 63;
      int ntkb = fr >> 6;
      int nt = ntkb >> 2, kb = ntkb & 3;
      int col = (nt << 4) + (lane & 15);
      int k0 = (kb << 5) + ((lane >> 4) << 3);
      unsigned short v[8];
#pragma unroll
      for (int i = 0; i < 8; ++i) {
        int k = k0 + i;
        float val;
        if (mat == 0) val = (k < 64) ? Wl1[k * 128 + col] : Wr1[(k - 64) * 128 + col];
        else          val = (col < 64) ? Wl2[k * 64 + col] : Wr2[k * 64 + (col - 64)];
        v[i] = bf16u(val);
      }
      *(uint4*)((mat ? W2p : W1p) + (size_t)fr * 8) = *(const uint4*)v;
    }
  }
}

// ---- scan NB bucket counts -> base (exclusive) + cursor init. 1 wave. ----
__global__ void k_scanb(const unsigned int* __restrict__ hist, unsigned int* __restrict__ base,
                        unsigned int* __restrict__ cursor, int NB) {
  const int lane = threadIdx.x;
  unsigned int running = 0;
  for (int b0 = 0; b0 < NB; b0 += 64) {
    int i = b0 + lane;
    unsigned int v = (i < NB) ? hist[i] : 0;
    unsigned int s = v;
#pragma unroll
    for (int off = 1; off < 64; off <<= 1) {
      unsigned int t = __shfl_up(s, off);
      if (lane >= off) s += t;
    }
    if (i < NB) {
      base[i] = running + s - v;
      cursor[i] = running + s - v;
    }
    running += __shfl(s, 63);
  }
  if (lane == 0) base[NB] = running;
}

// ---- partition edges into bucket regions; payload = src | (dst&127)<<25 ----
// Slim staging: u16 local edge-index permutation; write-out re-reads dst/src
// (permutation within a 32KB window -> L1). LDS 28.5KB -> 4 blocks/CU.
__global__ __launch_bounds__(512) void k_part(const int* __restrict__ src,
                                              const int* __restrict__ dst,
                                              unsigned int* __restrict__ cursor,
                                              unsigned int* __restrict__ bkt, int E, int NB) {
  __shared__ unsigned int histL[NBMAX], lbase[NBMAX], gpos[NBMAX], lcur[NBMAX];  // 12.5KB
  __shared__ unsigned short stage[8192];                                          // 16KB
  const int tid = threadIdx.x;
  const int e0 = blockIdx.x * 8192;
  const int m = min(8192, E - e0);
  for (int b = tid; b < NB; b += 512) { histL[b] = 0; lcur[b] = 0; }
  __syncthreads();
  for (int i = tid; i < m; i += 512) atomicAdd(&histL[(unsigned int)dst[e0 + i] >> 7], 1u);
  __syncthreads();
  if (tid < 64) {  // wave-0 exclusive scan of histL -> lbase
    unsigned int running = 0;
    for (int b0 = 0; b0 < NB; b0 += 64) {
      int i = b0 + tid;
      unsigned int v = (i < NB) ? histL[i] : 0;
      unsigned int s = v;
#pragma unroll
      for (int off = 1; off < 64; off <<= 1) {
        unsigned int t = __shfl_up(s, off);
        if (tid >= off) s += t;
      }
      if (i < NB) lbase[i] = running + s - v;
      running += __shfl(s, 63);
    }
  }
  __syncthreads();
  for (int b = tid; b < NB; b += 512) {
    unsigned int c = histL[b];
    gpos[b] = c ? atomicAdd(&cursor[b], c) : 0u;
  }
  for (int i = tid; i < m; i += 512) {
    unsigned int b = (unsigned int)dst[e0 + i] >> 7;
    unsigned int p = lbase[b] + atomicAdd(&lcur[b], 1u);
    stage[p] = (unsigned short)i;
  }
  __syncthreads();
  for (int i = tid; i < m; i += 512) {
    int idx = (int)stage[i];
    int d = dst[e0 + idx];          // L1-resident re-read
    int s = src[e0 + idx];
    unsigned int b = (unsigned int)d >> 7;
    bkt[gpos[b] + (unsigned int)i - lbase[b]] =
        (unsigned int)s | ((unsigned int)(d & 127) << 25);
  }
}

// ---- atomic-free bucketed mean-aggregation (proven r5/r6 gather loop) ----
// EPI=0: full counting sort; write back sorted edges (bkt) + degrees (degs);
//        gather xb -> bf16 agg rows.
// EPI=1: skip sort (load sorted bkt + degs); gather y2; fused
//        out = sigmoid(mean + z2 + b2).
template <int EPI>
__global__ __launch_bounds__(512) void k_aggs(const unsigned short* __restrict__ feat,  // bf16[N][64]
                                              unsigned int* __restrict__ bkt,
                                              const unsigned int* __restrict__ base,
                                              unsigned int* __restrict__ degs,
                                              unsigned short* __restrict__ outRows,
                                              const float* __restrict__ z2,
                                              const float* __restrict__ b2,
                                              float* __restrict__ outF, int N) {
  __shared__ unsigned int pbufA[BCAP];
  __shared__ unsigned int pbufB[BCAP];
  __shared__ unsigned int hist[128], lofs[128], cur[128];
  const int tid = threadIdx.x;
  const int lane = tid & 63;
  const int w = tid >> 6;  // 8 waves
  const int nodelo = blockIdx.x << 7;
  const int ebeg = (int)base[blockIdx.x];
  int m = (int)base[blockIdx.x + 1] - ebeg;
  m = (m > BCAP) ? BCAP : m;
  float bias = 0.f;
  if (EPI == 1) bias = b2[lane];

  if (EPI == 0) {
    if (tid < 128) hist[tid] = 0;
    __syncthreads();
    for (int i = tid; i < m; i += 512) {
      unsigned int t = bkt[ebeg + i];
      pbufA[i] = t;
      atomicAdd(&hist[t >> 25], 1u);
    }
    __syncthreads();
    if (tid < 64) {
      unsigned int v0 = hist[tid], v1 = hist[tid + 64];
      unsigned int s0 = v0, s1 = v1;
#pragma unroll
      for (int off = 1; off < 64; off <<= 1) {
        unsigned int t0 = __shfl_up(s0, off);
        unsigned int t1 = __shfl_up(s1, off);
        if (tid >= off) { s0 += t0; s1 += t1; }
      }
      unsigned int tot0 = __shfl(s0, 63);
      lofs[tid]      = s0 - v0;
      lofs[tid + 64] = tot0 + s1 - v1;
      cur[tid]       = s0 - v0;
      cur[tid + 64]  = tot0 + s1 - v1;
    }
    __syncthreads();
    for (int i = tid; i < m; i += 512) {
      unsigned int t = pbufA[i];
      unsigned int p = atomicAdd(&cur[t >> 25], 1u);
      pbufB[p] = t;
    }
    __syncthreads();
    // persist sorted order + degrees for pass 2
    for (int i = tid; i < m; i += 512) bkt[ebeg + i] = pbufB[i];
    if (tid < 128) degs[nodelo + tid] = hist[tid];
  } else {
    if (tid < 128) hist[tid] = degs[nodelo + tid];
    for (int i = tid; i < m; i += 512) pbufB[i] = bkt[ebeg + i];
    __syncthreads();
    if (tid < 64) {
      unsigned int v0 = hist[tid], v1 = hist[tid + 64];
      unsigned int s0 = v0, s1 = v1;
#pragma unroll
      for (int off = 1; off < 64; off <<= 1) {
        unsigned int t0 = __shfl_up(s0, off);
        unsigned int t1 = __shfl_up(s1, off);
        if (tid >= off) { s0 += t0; s1 += t1; }
      }
      unsigned int tot0 = __shfl(s0, 63);
      lofs[tid]      = s0 - v0;
      lofs[tid + 64] = tot0 + s1 - v1;
    }
    __syncthreads();
  }

  // Phase B: proven r5/r6 multi-tail gather (wave owns 16 nodes, lane = ch)
  for (int q = 0; q < 16; ++q) {
    const int r = (w << 4) + q;           // local node, wave-uniform
    const unsigned int c = hist[r];
    const unsigned int o = lofs[r];
    float acc = 0.f;
    unsigned int e = 0;
    for (; e + 8 <= c; e += 8) {
      int s0 = __builtin_amdgcn_readfirstlane((int)(pbufB[o + e + 0] & 0x1FFFFFFu));
      int s1 = __builtin_amdgcn_readfirstlane((int)(pbufB[o + e + 1] & 0x1FFFFFFu));
      int s2 = __builtin_amdgcn_readfirstlane((int)(pbufB[o + e + 2] & 0x1FFFFFFu));
      int s3 = __builtin_amdgcn_readfirstlane((int)(pbufB[o + e + 3] & 0x1FFFFFFu));
      int s4 = __builtin_amdgcn_readfirstlane((int)(pbufB[o + e + 4] & 0x1FFFFFFu));
      int s5 = __builtin_amdgcn_readfirstlane((int)(pbufB[o + e + 5] & 0x1FFFFFFu));
      int s6 = __builtin_amdgcn_readfirstlane((int)(pbufB[o + e + 6] & 0x1FFFFFFu));
      int s7 = __builtin_amdgcn_readfirstlane((int)(pbufB[o + e + 7] & 0x1FFFFFFu));
      float f0 = ldb(feat + ((size_t)s0 << 6) + lane);
      float f1 = ldb(feat + ((size_t)s1 << 6) + lane);
      float f2 = ldb(feat + ((size_t)s2 << 6) + lane);
      float f3 = ldb(feat + ((size_t)s3 << 6) + lane);
      float f4 = ldb(feat + ((size_t)s4 << 6) + lane);
      float f5 = ldb(feat + ((size_t)s5 << 6) + lane);
      float f6 = ldb(feat + ((size_t)s6 << 6) + lane);
      float f7 = ldb(feat + ((size_t)s7 << 6) + lane);
      acc += f0 + f1 + f2 + f3 + f4 + f5 + f6 + f7;
    }
    for (; e + 4 <= c; e += 4) {
      int s0 = __builtin_amdgcn_readfirstlane((int)(pbufB[o + e + 0] & 0x1FFFFFFu));
      int s1 = __builtin_amdgcn_readfirstlane((int)(pbufB[o + e + 1] & 0x1FFFFFFu));
      int s2 = __builtin_amdgcn_readfirstlane((int)(pbufB[o + e + 2] & 0x1FFFFFFu));
      int s3 = __builtin_amdgcn_readfirstlane((int)(pbufB[o + e + 3] & 0x1FFFFFFu));
      float f0 = ldb(feat + ((size_t)s0 << 6) + lane);
      float f1 = ldb(feat + ((size_t)s1 << 6) + lane);
      float f2 = ldb(feat + ((size_t)s2 << 6) + lane);
      float f3 = ldb(feat + ((size_t)s3 << 6) + lane);
      acc += f0 + f1 + f2 + f3;
    }
    for (; e < c; ++e) {
      int s0 = __builtin_amdgcn_readfirstlane((int)(pbufB[o + e] & 0x1FFFFFFu));
      acc += ldb(feat + ((size_t)s0 << 6) + lane);
    }
    const int node = nodelo + r;
    if (node < N) {
      float sc = c ? (1.f / (float)c) : 0.f;
      float v = acc * sc;
      if (EPI == 0) {
        outRows[((size_t)node << 6) + lane] = bf16u(v);
      } else {
        float t = v + z2[((size_t)node << 6) + lane] + bias;
        outF[((size_t)node << 6) + lane] = 1.f / (1.f + __expf(-t));
      }
    }
  }
}

// ---- fused MFMA: h = relu([agg|xb]@W1+b1) (LDS only); [y2|z2] = h@[Wl2|Wr2] ----
__global__ __launch_bounds__(256) void k_mmf(const unsigned short* __restrict__ agg,
                                             const unsigned short* __restrict__ xb,
                                             const unsigned short* __restrict__ W1p,
                                             const unsigned short* __restrict__ W2p,
                                             const float* __restrict__ b1,
                                             unsigned short* __restrict__ y2,
                                             float* __restrict__ z2, int N) {
  __shared__ __align__(16) unsigned short sH[64][136];  // 17.4 KB
  __shared__ __align__(16) unsigned short sY[64][72];   //  9.2 KB
  __shared__ __align__(16) float sZ[64][68];            // 17.4 KB
  const int tid = threadIdx.x;
  const int lane = tid & 63;
  const int w = tid >> 6;
  const int n0 = blockIdx.x << 6;
  const int row16 = lane & 15;
  const int kgrp = lane >> 4;
  int node = n0 + (w << 4) + row16;
  if (node >= N) node = N - 1;

  // ---- layer 1 ----
  bf16x8 a[4];
  {
    const unsigned short* ra = agg + ((size_t)node << 6);
    const unsigned short* rx = xb + ((size_t)node << 6);
    a[0] = *(const bf16x8*)(ra + kgrp * 8);
    a[1] = *(const bf16x8*)(ra + 32 + kgrp * 8);
    a[2] = *(const bf16x8*)(rx + kgrp * 8);
    a[3] = *(const bf16x8*)(rx + 32 + kgrp * 8);
  }
  const bf16x8* Wp1 = (const bf16x8*)W1p;
#pragma unroll
  for (int nt = 0; nt < 8; ++nt) {
    f32x4 acc = {0.f, 0.f, 0.f, 0.f};
#pragma unroll
    for (int kb = 0; kb < 4; ++kb) {
      bf16x8 b = Wp1[(nt * 4 + kb) * 64 + lane];
      acc = __builtin_amdgcn_mfma_f32_16x16x32_bf16(a[kb], b, acc, 0, 0, 0);
    }
    const int col = (nt << 4) + row16;
    const float bias = b1[col];
#pragma unroll
    for (int r = 0; r < 4; ++r) {
      int lrow = (w << 4) + (kgrp << 2) + r;
      sH[lrow][col] = bf16u(fmaxf(acc[r] + bias, 0.f));
    }
  }
  __syncthreads();
  // ---- layer 2: A-frags from LDS h-tile ----
  bf16x8 h4[4];
  {
    const int hr = (w << 4) + row16;
#pragma unroll
    for (int kb = 0; kb < 4; ++kb)
      h4[kb] = *(const bf16x8*)(&sH[hr][kb * 32 + kgrp * 8]);
  }
  const bf16x8* Wp2 = (const bf16x8*)W2p;
#pragma unroll
  for (int nt = 0; nt < 8; ++nt) {
    f32x4 acc = {0.f, 0.f, 0.f, 0.f};
#pragma unroll
    for (int kb = 0; kb < 4; ++kb) {
      bf16x8 b = Wp2[(nt * 4 + kb) * 64 + lane];
      acc = __builtin_amdgcn_mfma_f32_16x16x32_bf16(h4[kb], b, acc, 0, 0, 0);
    }
    const int col = (nt << 4) + row16;
#pragma unroll
    for (int r = 0; r < 4; ++r) {
      int lrow = (w << 4) + (kgrp << 2) + r;
      if (nt < 4) sY[lrow][col] = bf16u(acc[r]);
      else        sZ[lrow][col - 64] = acc[r];
    }
  }
  __syncthreads();
  // y2: 64 rows x 64 bf16 = 512 x 16B
#pragma unroll
  for (int it = 0; it < 2; ++it) {
    int idx = it * 256 + tid;
    int r = idx >> 3, sub = idx & 7;
    int nn = n0 + r;
    if (nn < N)
      *(uint4*)((char*)(y2 + ((size_t)nn << 6)) + sub * 16) =
          *(const uint4*)((char*)&sY[r][0] + sub * 16);
  }
  // z2: 64 rows x 64 f32 = 1024 x 16B
#pragma unroll
  for (int it = 0; it < 4; ++it) {
    int idx = it * 256 + tid;
    int r = idx >> 4, sub = idx & 15;
    int nn = n0 + r;
    if (nn < N)
      *(uint4*)((char*)(z2 + ((size_t)nn << 6)) + sub * 16) =
          *(const uint4*)((char*)&sZ[r][0] + sub * 16);
  }
}

extern "C" void kernel_launch(void* const* d_in, const int* in_sizes, int n_in,
                              void* d_out, int out_size, void* d_ws, size_t ws_size,
                              hipStream_t stream) {
  const float* x   = (const float*)d_in[0];
  const int*   ei  = (const int*)d_in[1];
  const float* Wl1 = (const float*)d_in[2];
  const float* Wr1 = (const float*)d_in[3];
  const float* b1  = (const float*)d_in[4];
  const float* Wl2 = (const float*)d_in[5];
  const float* Wr2 = (const float*)d_in[6];
  const float* b2  = (const float*)d_in[7];
  float* out = (float*)d_out;

  const int N = in_sizes[0] / 64;
  const int E = in_sizes[1] / 2;
  int NB = (N + 127) >> 7;
  if (NB > NBMAX) NB = NBMAX;
  const int* src = ei;
  const int* dst = ei + E;

  char* wp = (char*)d_ws;
  auto take = [&](size_t bytes) {
    char* p = wp;
    wp += (bytes + 255) & ~(size_t)255;
    return p;
  };
  unsigned int* hist   = (unsigned int*)take((size_t)NBMAX * 4);
  unsigned int* base   = (unsigned int*)take((size_t)(NBMAX + 1) * 4);
  unsigned int* cursor = (unsigned int*)take((size_t)NBMAX * 4);
  unsigned int* bkt    = (unsigned int*)take((size_t)E * 4);
  unsigned int* degs   = (unsigned int*)take((size_t)NBMAX * 128 * 4);
  unsigned short* W1p  = (unsigned short*)take(128 * 128 * 2);
  unsigned short* W2p  = (unsigned short*)take(128 * 128 * 2);
  unsigned short* xb   = (unsigned short*)take((size_t)N * 64 * 2);
  unsigned short* agg  = (unsigned short*)take((size_t)N * 64 * 2);
  unsigned short* y2   = (unsigned short*)take((size_t)N * 64 * 2);
  float* z2            = (float*)take((size_t)N * 64 * 4);

  hipMemsetAsync(hist, 0, (size_t)NBMAX * 4, stream);

  const int castB = (N * 16 + 255) / 256;
  const int histB = (E + 16383) / 16384;
  k_prep<<<castB + histB + 16, 256, 0, stream>>>(x, xb, dst, hist, Wl1, Wr1, Wl2, Wr2,
                                                 W1p, W2p, N, E, NB, castB, histB);
  k_scanb<<<1, 64, 0, stream>>>(hist, base, cursor, NB);
  k_part<<<(E + 8191) / 8192, 512, 0, stream>>>(src, dst, cursor, bkt, E, NB);

  const int nb64 = (N + 63) / 64;
  k_aggs<0><<<NB, 512, 0, stream>>>(xb, bkt, base, degs, agg, nullptr, nullptr, nullptr, N);
  k_mmf<<<nb64, 256, 0, stream>>>(agg, xb, W1p, W2p, b1, y2, z2, N);
  k_aggs<1><<<NB, 512, 0, stream>>>(y2, bkt, base, degs, nullptr, z2, b2, out, N);
}